// Round 1
// baseline (101.351 us; speedup 1.0000x reference)
//
#include <hip/hip_runtime.h>

typedef _Float16 f16;
typedef _Float16 f16x8 __attribute__((ext_vector_type(8)));
typedef _Float16 f16x4 __attribute__((ext_vector_type(4)));
typedef float f32x4 __attribute__((ext_vector_type(4)));

#define MFMA16(a, b, c) __builtin_amdgcn_mfma_f32_16x16x32_f16(a, b, c, 0, 0, 0)

constexpr int Bn = 8, Sn = 2048, En = 1024, Hn = 64;
constexpr int Mn = Bn * Sn;  // 16384

// ---------------------------------------------------------------------------
// Kernel A: fused QKV projection. out = x @ W^T + b, emitted as fp16.
// Q: [B,S,H], K: [B,S,H], VT: [B,H,S]
// ---------------------------------------------------------------------------
__global__ __launch_bounds__(256) void proj_kernel(
    const float* __restrict__ x,
    const float* __restrict__ Wq, const float* __restrict__ bq,
    const float* __restrict__ Wk, const float* __restrict__ bk,
    const float* __restrict__ Wv, const float* __restrict__ bv,
    f16* __restrict__ qws, f16* __restrict__ kws, f16* __restrict__ vtws)
{
    __shared__ f16 Wlds[192 * 72];  // 192 rows (Q|K|V x 64), stride 72 halves
    const int tid = threadIdx.x;
    const int w = tid >> 6, l = tid & 63;
    const int l15 = l & 15, lhi = l >> 4;
    const int Mbase = blockIdx.x * 64;
    const int arow = Mbase + w * 16 + l15;  // A-fragment row for this lane
    const float* xrow = x + (size_t)arow * En;

    f32x4 acc[12];
#pragma unroll
    for (int i = 0; i < 12; ++i) acc[i] = (f32x4){0.f, 0.f, 0.f, 0.f};

    const float* Wsrc0 = Wq; const float* Wsrc1 = Wk; const float* Wsrc2 = Wv;

    for (int kb = 0; kb < En; kb += 64) {
        // stage W tile [192][64] fp32 -> fp16 LDS
#pragma unroll
        for (int j = 0; j < 12; ++j) {
            int i = tid + 256 * j;
            int r = i >> 4, c4 = i & 15;
            const float* src = (r < 64 ? Wsrc0 : (r < 128 ? Wsrc1 : Wsrc2))
                               + (size_t)(r & 63) * En + kb + c4 * 4;
            float4 v = *reinterpret_cast<const float4*>(src);
            f16x4 hv = {(f16)v.x, (f16)v.y, (f16)v.z, (f16)v.w};
            *reinterpret_cast<f16x4*>(&Wlds[r * 72 + c4 * 4]) = hv;
        }
        __syncthreads();
        // A fragments from x (fp32 -> fp16)
        f16x8 a[2];
#pragma unroll
        for (int kc = 0; kc < 2; ++kc) {
            const float* ap = xrow + kb + kc * 32 + lhi * 8;
            float4 v0 = *reinterpret_cast<const float4*>(ap);
            float4 v1 = *reinterpret_cast<const float4*>(ap + 4);
            a[kc] = (f16x8){(f16)v0.x, (f16)v0.y, (f16)v0.z, (f16)v0.w,
                            (f16)v1.x, (f16)v1.y, (f16)v1.z, (f16)v1.w};
        }
#pragma unroll
        for (int nt = 0; nt < 12; ++nt) {
#pragma unroll
            for (int kc = 0; kc < 2; ++kc) {
                f16x8 b = *reinterpret_cast<const f16x8*>(
                    &Wlds[(nt * 16 + l15) * 72 + kc * 32 + lhi * 8]);
                acc[nt] = MFMA16(a[kc], b, acc[nt]);
            }
        }
        __syncthreads();
    }

    // epilogue: bias add, fp16 convert, store Q/K/VT
    const int batch = Mbase >> 11;
    const int r0 = Mbase + w * 16 + lhi * 4;  // first of 4 C/D rows
#pragma unroll
    for (int nt = 0; nt < 12; ++nt) {
        const int set = nt >> 2;
        const int h = (nt & 3) * 16 + l15;
        const float bias = (set == 0 ? bq : (set == 1 ? bk : bv))[h];
        if (set == 0) {
#pragma unroll
            for (int r = 0; r < 4; ++r)
                qws[(size_t)(r0 + r) * Hn + h] = (f16)(acc[nt][r] + bias);
        } else if (set == 1) {
#pragma unroll
            for (int r = 0; r < 4; ++r)
                kws[(size_t)(r0 + r) * Hn + h] = (f16)(acc[nt][r] + bias);
        } else {
            const int s0 = r0 & (Sn - 1);
            f16x4 hv = {(f16)(acc[nt][0] + bias), (f16)(acc[nt][1] + bias),
                        (f16)(acc[nt][2] + bias), (f16)(acc[nt][3] + bias)};
            *reinterpret_cast<f16x4*>(
                &vtws[(size_t)batch * Hn * Sn + (size_t)h * Sn + s0]) = hv;
        }
    }
}

// ---------------------------------------------------------------------------
// Kernel B: causal flash attention. One 16-row q-tile per WG; 4 waves split
// the key range and combine (m, l, O) partials through LDS.
// ---------------------------------------------------------------------------
__global__ __launch_bounds__(256) void attn_kernel(
    const f16* __restrict__ qws, const f16* __restrict__ kws,
    const f16* __restrict__ vtws, float* __restrict__ out)
{
    __shared__ f16 Plds[4][16 * 56];   // per-wave P tile, stride 56 halves
    __shared__ float OL[4][16][64];
    __shared__ float mL[4][16];
    __shared__ float lL[4][16];

    const int tid = threadIdx.x;
    const int w = tid >> 6, l = tid & 63;
    const int l15 = l & 15, lhi = l >> 4;

    const int tg = (blockIdx.x * 997) & 1023;  // balance causal ramp across CUs
    const int batch = tg >> 7;
    const int qbase = (tg & 127) * 16;

    const f16* qb = qws + (size_t)batch * Sn * Hn;
    const f16* kb = kws + (size_t)batch * Sn * Hn;
    const f16* vtb = vtws + (size_t)batch * Hn * Sn;

    // Q fragments (A-operand), rows = qbase + (l&15)
    f16x8 qf[2];
#pragma unroll
    for (int kc = 0; kc < 2; ++kc)
        qf[kc] = *reinterpret_cast<const f16x8*>(
            &qb[(size_t)(qbase + l15) * Hn + kc * 32 + lhi * 8]);

    f32x4 O[4];
#pragma unroll
    for (int i = 0; i < 4; ++i) O[i] = (f32x4){0.f, 0.f, 0.f, 0.f};
    float m4[4], l4[4];
#pragma unroll
    for (int r = 0; r < 4; ++r) { m4[r] = -1e30f; l4[r] = 0.f; }

    const int nkt = (qbase + 16 + 31) >> 5;  // key tiles of 32
    for (int kt = w; kt < nkt; kt += 4) {
        const int kbase = kt * 32;
        // S = Q @ K^T  (two 16-key column tiles)
        f32x4 Sv[2];
#pragma unroll
        for (int nt = 0; nt < 2; ++nt) {
            f32x4 sacc = (f32x4){0.f, 0.f, 0.f, 0.f};
#pragma unroll
            for (int kc = 0; kc < 2; ++kc) {
                f16x8 kf = *reinterpret_cast<const f16x8*>(
                    &kb[(size_t)(kbase + nt * 16 + l15) * Hn + kc * 32 + lhi * 8]);
                sacc = MFMA16(qf[kc], kf, sacc);
            }
            Sv[nt] = sacc;
        }
        // scale by 8 (reference multiplies by sqrt(H)) + causal mask
        float t[2][4];
#pragma unroll
        for (int nt = 0; nt < 2; ++nt) {
            const int key = kbase + nt * 16 + l15;
#pragma unroll
            for (int r = 0; r < 4; ++r) {
                const int qr = qbase + lhi * 4 + r;
                t[nt][r] = (key <= qr) ? Sv[nt][r] * 8.0f : -1e30f;
            }
        }
        // online softmax: row max (reduce across the 16 key-lanes)
        float mnew[4], alpha[4];
#pragma unroll
        for (int r = 0; r < 4; ++r) {
            float mx = fmaxf(t[0][r], t[1][r]);
            mx = fmaxf(mx, __shfl_xor(mx, 1));
            mx = fmaxf(mx, __shfl_xor(mx, 2));
            mx = fmaxf(mx, __shfl_xor(mx, 4));
            mx = fmaxf(mx, __shfl_xor(mx, 8));
            mnew[r] = fmaxf(m4[r], mx);
            alpha[r] = __expf(m4[r] - mnew[r]);
            m4[r] = mnew[r];
        }
        // P = exp(t - m)  (explicit zero on masked entries), row sums
        float p[2][4];
#pragma unroll
        for (int r = 0; r < 4; ++r) {
            p[0][r] = (t[0][r] > -9e29f) ? __expf(t[0][r] - mnew[r]) : 0.f;
            p[1][r] = (t[1][r] > -9e29f) ? __expf(t[1][r] - mnew[r]) : 0.f;
            float s = p[0][r] + p[1][r];
            s += __shfl_xor(s, 1);
            s += __shfl_xor(s, 2);
            s += __shfl_xor(s, 4);
            s += __shfl_xor(s, 8);
            l4[r] = l4[r] * alpha[r] + s;
        }
        // P (C/D layout) -> LDS -> A-fragment layout
#pragma unroll
        for (int nt = 0; nt < 2; ++nt)
#pragma unroll
            for (int r = 0; r < 4; ++r)
                Plds[w][(lhi * 4 + r) * 56 + nt * 16 + l15] = (f16)p[nt][r];
        f16x8 pa = *reinterpret_cast<const f16x8*>(&Plds[w][l15 * 56 + lhi * 8]);
        // rescale O, accumulate P @ V
#pragma unroll
        for (int nt = 0; nt < 4; ++nt) {
#pragma unroll
            for (int r = 0; r < 4; ++r) O[nt][r] *= alpha[r];
            f16x8 vf = *reinterpret_cast<const f16x8*>(
                &vtb[(size_t)(nt * 16 + l15) * Sn + kbase + lhi * 8]);
            O[nt] = MFMA16(pa, vf, O[nt]);
        }
    }

    // publish per-wave partials
#pragma unroll
    for (int nt = 0; nt < 4; ++nt)
#pragma unroll
        for (int r = 0; r < 4; ++r)
            OL[w][lhi * 4 + r][nt * 16 + l15] = O[nt][r];
    if (l15 == 0) {
#pragma unroll
        for (int r = 0; r < 4; ++r) {
            mL[w][lhi * 4 + r] = m4[r];
            lL[w][lhi * 4 + r] = l4[r];
        }
    }
    __syncthreads();

    // combine 4 partials; thread t -> row t>>4, cols (t&15)*4 .. +3
    {
        const int row = tid >> 4, c0 = (tid & 15) * 4;
        float mg = fmaxf(fmaxf(mL[0][row], mL[1][row]),
                         fmaxf(mL[2][row], mL[3][row]));
        float den = 0.f;
        float num[4] = {0.f, 0.f, 0.f, 0.f};
#pragma unroll
        for (int ww = 0; ww < 4; ++ww) {
            float sc = __expf(mL[ww][row] - mg);
            den += lL[ww][row] * sc;
#pragma unroll
            for (int c = 0; c < 4; ++c) num[c] += OL[ww][row][c0 + c] * sc;
        }
        const float inv = 1.0f / den;
        float4 o = {num[0] * inv, num[1] * inv, num[2] * inv, num[3] * inv};
        *reinterpret_cast<float4*>(
            &out[((size_t)batch * Sn + qbase + row) * Hn + c0]) = o;
    }
}

// ---------------------------------------------------------------------------
extern "C" void kernel_launch(void* const* d_in, const int* in_sizes, int n_in,
                              void* d_out, int out_size, void* d_ws, size_t ws_size,
                              hipStream_t stream) {
    const float* x  = (const float*)d_in[0];
    const float* Wk = (const float*)d_in[1];
    const float* bk = (const float*)d_in[2];
    const float* Wq = (const float*)d_in[3];
    const float* bq = (const float*)d_in[4];
    const float* Wv = (const float*)d_in[5];
    const float* bv = (const float*)d_in[6];

    f16* qws  = (f16*)d_ws;
    f16* kws  = qws + (size_t)Mn * Hn;
    f16* vtws = kws + (size_t)Mn * Hn;

    proj_kernel<<<256, 256, 0, stream>>>(x, Wq, bq, Wk, bk, Wv, bv,
                                         qws, kws, vtws);
    attn_kernel<<<1024, 256, 0, stream>>>(qws, kws, vtws, (float*)d_out);
}